// Round 1
// 10688.287 us; speedup vs baseline: 2.9473x; 2.9473x over previous
//
#include <hip/hip_runtime.h>

#define N_SEQ 2047
#define DIM   512
#define RANK  64
#define VOCAB 32000
#define SCALE 0.125f
#define LN_EPS 1e-5f

typedef __attribute__((ext_vector_type(4))) float  floatx4;
typedef __attribute__((ext_vector_type(8))) __bf16 bf16x8;
typedef __attribute__((ext_vector_type(4))) unsigned short ushortx4;

__device__ __forceinline__ unsigned short f2bf(float x) {
    unsigned int u = __builtin_bit_cast(unsigned int, x);
    return (unsigned short)((u + 0x7fffu + ((u >> 16) & 1u)) >> 16);
}

// DPP-based wave64 sum reduction (identity 0), result broadcast from lane 63.
__device__ __forceinline__ float wave_sum64(float x) {
    int xi;
    xi = __builtin_amdgcn_update_dpp(0, __float_as_int(x), 0x111, 0xf, 0xf, false); x += __int_as_float(xi); // row_shr:1
    xi = __builtin_amdgcn_update_dpp(0, __float_as_int(x), 0x112, 0xf, 0xf, false); x += __int_as_float(xi); // row_shr:2
    xi = __builtin_amdgcn_update_dpp(0, __float_as_int(x), 0x114, 0xf, 0xf, false); x += __int_as_float(xi); // row_shr:4
    xi = __builtin_amdgcn_update_dpp(0, __float_as_int(x), 0x118, 0xf, 0xf, false); x += __int_as_float(xi); // row_shr:8
    xi = __builtin_amdgcn_update_dpp(0, __float_as_int(x), 0x142, 0xa, 0xf, false); x += __int_as_float(xi); // row_bcast15 -> rows 1,3
    xi = __builtin_amdgcn_update_dpp(0, __float_as_int(x), 0x143, 0x8, 0xf, false); x += __int_as_float(xi); // row_bcast31 -> row 3
    return __int_as_float(__builtin_amdgcn_readlane(__float_as_int(x), 63));
}

// ---------------------------------------------------------------- embedding
__global__ __launch_bounds__(128) void k_embed(const int* __restrict__ ids,
                                               const float* __restrict__ E,
                                               float* __restrict__ s,
                                               float* __restrict__ q) {
    int n = blockIdx.x;
    int id = ids[n + 1];
    float4 v = ((const float4*)(E + (size_t)id * DIM))[threadIdx.x];
    ((float4*)(s + (size_t)n * DIM))[threadIdx.x] = v;
    ((float4*)(q + (size_t)n * DIM))[threadIdx.x] = v;
}

// ---------------------------------------------------------------- qr/xv projections
__global__ __launch_bounds__(384) void k_proj(const float* __restrict__ s,
                                              const float* __restrict__ Ur,
                                              const float* __restrict__ Vr,
                                              float* __restrict__ qr,
                                              float* __restrict__ xv) {
    __shared__ float s8[8 * DIM];
    int t0 = blockIdx.x * 8;
    for (int i = threadIdx.x; i < 8 * DIM; i += 384) {
        int t = t0 + (i >> 9);
        s8[i] = (t < N_SEQ) ? s[(size_t)t * DIM + (i & 511)] : 0.f;
    }
    __syncthreads();
    int c = threadIdx.x;
    int l = (c % 192) / 64;
    int r = c & 63;
    const float* W = ((c < 192) ? Ur : Vr) + (size_t)l * DIM * RANK + r;
    float acc[8] = {};
    for (int d = 0; d < DIM; d++) {
        float w = W[(size_t)d * RANK];
        #pragma unroll
        for (int i = 0; i < 8; i++) acc[i] += s8[i * DIM + d] * w;
    }
    float* out = ((c < 192) ? qr : xv) + (size_t)l * N_SEQ * RANK;
    #pragma unroll
    for (int i = 0; i < 8; i++) {
        int t = t0 + i;
        if (t < N_SEQ) out[(size_t)t * RANK + r] = acc[i];
    }
}

// ---------------------------------------------------------------- kr0 = M0 @ Vr[l]
__global__ __launch_bounds__(64) void k_kr0(const float* __restrict__ m0,
                                            const float* __restrict__ m1,
                                            const float* __restrict__ m2,
                                            const float* __restrict__ Vr,
                                            float* __restrict__ kr) {
    __shared__ float mrow[DIM];
    int sl = blockIdx.x;
    int lvl = (sl < 256) ? 0 : (sl < 320 ? 1 : 2);
    const float* src = (lvl == 0) ? m0 + (size_t)sl * DIM
                     : (lvl == 1) ? m1 + (size_t)(sl - 256) * DIM
                                  : m2 + (size_t)(sl - 320) * DIM;
    for (int i = threadIdx.x; i < DIM / 4; i += 64)
        ((float4*)mrow)[i] = ((const float4*)src)[i];
    __syncthreads();
    const float* W = Vr + (size_t)lvl * DIM * RANK + threadIdx.x;
    float acc = 0.f;
    for (int d = 0; d < DIM; d++) acc += mrow[d] * W[(size_t)d * RANK];
    kr[(size_t)sl * RANK + threadIdx.x] = acc;
}

// ---------------------------------------------------------------- Phase A: selection scan
// One wave per level. kr register-resident (G slots/lane). Per step:
//   scores (register FMA) -> 16th-largest via ballot binary search -> softmax
//   weights (shift by threshold, DPP sum) -> store (w, slot) pairs -> gated kr update.
// qr/xv LDS double-buffered in 64-step chunks, trickle-staged one step per iteration.
#define SELECT_BODY(T, QC, QN) { \
    const int t_  = (T); \
    const int tt_ = t_ & 63; \
    const int buf_ = (t_ >> 6) & 1; \
    const int tstage_ = (t_ & ~63) + 64 + tt_; \
    if (tstage_ < N_SEQ) { \
        const float a_ = qrl[(size_t)tstage_ * RANK + lane]; \
        const float c_ = xvl[(size_t)tstage_ * RANK + lane]; \
        qs[(((buf_ ^ 1) << 6) + tt_) * 64 + lane] = a_; \
        xs[(((buf_ ^ 1) << 6) + tt_) * 64 + lane] = c_; \
    } \
    float acc_[G]; \
    _Pragma("unroll") for (int g = 0; g < G; ++g) acc_[g] = 0.f; \
    _Pragma("unroll") for (int rq = 0; rq < 16; ++rq) { \
        const float4 qf_ = QC[rq]; \
        _Pragma("unroll") for (int g = 0; g < G; ++g) { \
            acc_[g] += qf_.x * krr[g][rq * 4 + 0]; \
            acc_[g] += qf_.y * krr[g][rq * 4 + 1]; \
            acc_[g] += qf_.z * krr[g][rq * 4 + 2]; \
            acc_[g] += qf_.w * krr[g][rq * 4 + 3]; \
        } \
    } \
    { const int tn_ = t_ + 1; \
      const int off_ = ((((tn_ >> 6) & 1) << 6) + (tn_ & 63)) * 64; \
      _Pragma("unroll") for (int rq = 0; rq < 16; ++rq) QN[rq] = ((const float4*)(qs + off_))[rq]; } \
    float scf_[G]; unsigned key_[G]; \
    _Pragma("unroll") for (int g = 0; g < G; ++g) { \
        scf_[g] = acc_[g] * SCALE; \
        const unsigned b_ = __float_as_uint(scf_[g]); \
        const unsigned u_ = (b_ & 0x80000000u) ? ~b_ : (b_ | 0x80000000u); \
        key_[g] = ((g << 6) + lane < S) ? u_ : 0u; \
    } \
    unsigned thr_ = 0u; \
    _Pragma("unroll") for (int bit = 31; bit >= 0; --bit) { \
        const unsigned cand_ = thr_ | (1u << bit); \
        int cnt_ = 0; \
        _Pragma("unroll") for (int g = 0; g < G; ++g) cnt_ += (int)__popcll(__ballot(key_[g] >= cand_)); \
        if (cnt_ >= 16) thr_ = cand_; \
    } \
    unsigned long long beq_[G]; unsigned long long bsel_[G]; bool selq_[G]; \
    int cntgt_ = 0; \
    _Pragma("unroll") for (int g = 0; g < G; ++g) { \
        cntgt_ += (int)__popcll(__ballot(key_[g] > thr_)); \
        beq_[g] = __ballot(key_[g] == thr_); \
    } \
    const int needeq_ = 16 - cntgt_; \
    int eqpre_ = 0; \
    _Pragma("unroll") for (int g = 0; g < G; ++g) { \
        const bool isgt_ = key_[g] > thr_; \
        const bool iseq_ = key_[g] == thr_; \
        const int eqrank_ = eqpre_ + (int)__popcll(beq_[g] & ltmask); \
        selq_[g] = isgt_ || (iseq_ && (eqrank_ < needeq_)); \
        bsel_[g] = __ballot(selq_[g]); \
        eqpre_ += (int)__popcll(beq_[g]); \
    } \
    const unsigned tb_ = (thr_ & 0x80000000u) ? (thr_ & 0x7fffffffu) : ~thr_; \
    const float Tf_ = __uint_as_float(tb_); \
    float e_[G]; float es_ = 0.f; \
    _Pragma("unroll") for (int g = 0; g < G; ++g) { \
        e_[g] = selq_[g] ? expf(scf_[g] - Tf_) : 0.f; \
        es_ += e_[g]; \
    } \
    const float inv_ = 1.f / wave_sum64(es_); \
    int pb_ = 0; \
    _Pragma("unroll") for (int g = 0; g < G; ++g) { \
        if (selq_[g]) { \
            const int pos_ = pb_ + (int)__popcll(bsel_[g] & ltmask); \
            float2 o_; o_.x = e_[g] * inv_; o_.y = __int_as_float((g << 6) + lane); \
            selo[(size_t)t_ * 16 + pos_] = o_; \
        } \
        pb_ += (int)__popcll(bsel_[g]); \
    } \
    if ((t_ & IMASK) == 0) { \
        const float* xrow_ = xs + (((size_t)buf_ << 6) + tt_) * 64; \
        _Pragma("unroll") for (int rq = 0; rq < 16; ++rq) { \
            const float4 xf_ = ((const float4*)xrow_)[rq]; \
            _Pragma("unroll") for (int g = 0; g < G; ++g) { \
                const float wg_ = e_[g] * inv_; \
                krr[g][rq * 4 + 0] += wg_ * xf_.x; \
                krr[g][rq * 4 + 1] += wg_ * xf_.y; \
                krr[g][rq * 4 + 2] += wg_ * xf_.z; \
                krr[g][rq * 4 + 3] += wg_ * xf_.w; \
            } \
        } \
    } \
}

template<int S, int IMASK>
__device__ __forceinline__ void select_impl(float* qs, float* xs,
                                            const float* __restrict__ qrl,
                                            const float* __restrict__ xvl,
                                            const float* __restrict__ krl,
                                            float2* __restrict__ selo) {
    constexpr int G = (S + 63) / 64;
    const int lane = threadIdx.x;
    const unsigned long long ltmask = (1ULL << lane) - 1ULL;

    float krr[G][RANK];
    #pragma unroll
    for (int g = 0; g < G; ++g) {
        const int slot = (g << 6) + lane;
        if (slot < S) {
            #pragma unroll
            for (int rq = 0; rq < 16; ++rq) {
                float4 v = ((const float4*)(krl + (size_t)slot * RANK))[rq];
                krr[g][rq * 4 + 0] = v.x; krr[g][rq * 4 + 1] = v.y;
                krr[g][rq * 4 + 2] = v.z; krr[g][rq * 4 + 3] = v.w;
            }
        } else {
            #pragma unroll
            for (int r = 0; r < RANK; ++r) krr[g][r] = 0.f;
        }
    }

    // prologue: stage chunk 0 (t = 0..63) into buffer 0
    for (int i = 0; i < 64; ++i) {
        qs[i * 64 + lane] = qrl[(size_t)i * RANK + lane];
        xs[i * 64 + lane] = xvl[(size_t)i * RANK + lane];
    }
    __syncthreads();

    float4 qvA[16], qvB[16];
    #pragma unroll
    for (int rq = 0; rq < 16; ++rq) qvA[rq] = ((const float4*)qs)[rq];

    int t = 0;
    for (; t + 1 < N_SEQ; t += 2) {
        SELECT_BODY(t,     qvA, qvB);
        SELECT_BODY(t + 1, qvB, qvA);
    }
    SELECT_BODY(t, qvA, qvB);   // t == N_SEQ-1 (even)
}

__global__ __launch_bounds__(64, 1) void k_select_all(const float* __restrict__ qr,
                                                      const float* __restrict__ xv,
                                                      const float* __restrict__ kr0,
                                                      float2* __restrict__ sel) {
    __shared__ float qs[2 * 64 * 64];
    __shared__ float xs[2 * 64 * 64];
    const int l = blockIdx.x;
    if (l == 0)
        select_impl<256, 0>(qs, xs, qr, xv, kr0, sel);
    else if (l == 1)
        select_impl<64, 3>(qs, xs, qr + (size_t)N_SEQ * RANK, xv + (size_t)N_SEQ * RANK,
                           kr0 + 256 * RANK, sel + (size_t)N_SEQ * 16);
    else
        select_impl<16, 15>(qs, xs, qr + (size_t)2 * N_SEQ * RANK, xv + (size_t)2 * N_SEQ * RANK,
                            kr0 + 320 * RANK, sel + (size_t)2 * N_SEQ * 16);
}

// ---------------------------------------------------------------- Phase B: apply scan
// Column-parallel: each block owns 64 columns of one level's M (LDS-resident) and
// replays the precomputed (w, slot) selections, accumulating read contributions into q.
template<int S, int IMASK>
__device__ __forceinline__ void apply_impl(float* Ml,
                                           const float* __restrict__ sA,
                                           const float2* __restrict__ selo,
                                           const float* __restrict__ Msrc,
                                           float* __restrict__ q, int chunk) {
    const int lane = threadIdx.x;
    const int c0 = chunk * 64;
    for (int sl = 0; sl < S; ++sl)
        Ml[sl * 64 + lane] = Msrc[(size_t)sl * DIM + c0 + lane];
    __syncthreads();

    float4 svc[8];
    #pragma unroll
    for (int k = 0; k < 8; ++k) svc[k] = ((const float4*)selo)[k];
    float scc = sA[c0 + lane];

    for (int t = 0; t < N_SEQ; ++t) {
        float4 svn[8]; float scn;
        const int tn = (t + 1 < N_SEQ) ? t + 1 : t;
        #pragma unroll
        for (int k = 0; k < 8; ++k) svn[k] = ((const float4*)(selo + (size_t)tn * 16))[k];
        scn = sA[(size_t)tn * DIM + c0 + lane];

        const bool gate = (t & IMASK) == 0;
        float acc = 0.f;
        #pragma unroll
        for (int k = 0; k < 8; ++k) {
            const float w0 = svc[k].x; const int i0 = __float_as_int(svc[k].y);
            const float w1 = svc[k].z; const int i1 = __float_as_int(svc[k].w);
            const float m0v = Ml[i0 * 64 + lane];
            const float m1v = Ml[i1 * 64 + lane];
            acc += w0 * m0v;
            acc += w1 * m1v;
            if (gate) {
                Ml[i0 * 64 + lane] = m0v + w0 * scc;
                Ml[i1 * 64 + lane] = m1v + w1 * scc;
            }
        }
        atomicAdd(&q[(size_t)t * DIM + c0 + lane], acc);
        #pragma unroll
        for (int k = 0; k < 8; ++k) svc[k] = svn[k];
        scc = scn;
    }
}

__global__ __launch_bounds__(64) void k_apply_all(const float* __restrict__ s,
                                                  const float2* __restrict__ sel,
                                                  const float* __restrict__ m0,
                                                  const float* __restrict__ m1,
                                                  const float* __restrict__ m2,
                                                  float* __restrict__ q) {
    __shared__ float Ml[256 * 64];
    const int b = blockIdx.x;
    if (b < 8)
        apply_impl<256, 0>(Ml, s, sel, m0, q, b);
    else if (b < 16)
        apply_impl<64, 3>(Ml, s, sel + (size_t)N_SEQ * 16, m1, q, b - 8);
    else
        apply_impl<16, 15>(Ml, s, sel + (size_t)2 * N_SEQ * 16, m2, q, b - 16);
}

// ---------------------------------------------------------------- h = LN(q @ Wproj^T)
__global__ __launch_bounds__(256) void k_wproj_ln(const float* __restrict__ q,
                                                  const float* __restrict__ Wp,
                                                  const float* __restrict__ g,
                                                  const float* __restrict__ b,
                                                  float* __restrict__ h) {
    __shared__ float q8[8 * DIM];
    __shared__ float hp[8 * DIM];
    int t0 = blockIdx.x * 8;
    for (int i = threadIdx.x; i < 8 * DIM; i += 256) {
        int t = t0 + (i >> 9);
        q8[i] = (t < N_SEQ) ? q[(size_t)t * DIM + (i & 511)] : 0.f;
    }
    __syncthreads();
    int c0 = threadIdx.x * 2;
    float acc0[8] = {}, acc1[8] = {};
    const float* w0 = Wp + (size_t)c0 * DIM;
    const float* w1 = w0 + DIM;
    for (int d = 0; d < DIM; d++) {
        float a0 = w0[d], a1 = w1[d];
        #pragma unroll
        for (int i = 0; i < 8; i++) {
            float qv = q8[i * DIM + d];
            acc0[i] += qv * a0;
            acc1[i] += qv * a1;
        }
    }
    #pragma unroll
    for (int i = 0; i < 8; i++) {
        hp[i * DIM + c0]     = acc0[i];
        hp[i * DIM + c0 + 1] = acc1[i];
    }
    __syncthreads();
    int rowi = threadIdx.x >> 5;
    int l32  = threadIdx.x & 31;
    int t = t0 + rowi;
    if (t < N_SEQ) {
        float sum = 0.f, sq = 0.f;
        #pragma unroll
        for (int u = 0; u < 16; u++) {
            float x = hp[rowi * DIM + l32 + u * 32];
            sum += x; sq += x * x;
        }
        #pragma unroll
        for (int off = 16; off >= 1; off >>= 1) {
            sum += __shfl_xor(sum, off, 32);
            sq  += __shfl_xor(sq,  off, 32);
        }
        float mean = sum * (1.f / DIM);
        float var  = sq * (1.f / DIM) - mean * mean;
        float inv  = rsqrtf(var + LN_EPS);
        #pragma unroll
        for (int u = 0; u < 16; u++) {
            int d = l32 + u * 32;
            float x = hp[rowi * DIM + d];
            h[(size_t)t * DIM + d] = (x - mean) * inv * g[d] + b[d];
        }
    }
}

// ---------------------------------------------------------------- a = h@Wq, kf = h@Wk
__global__ __launch_bounds__(128) void k_qk(const float* __restrict__ h,
                                            const float* __restrict__ Wq,
                                            const float* __restrict__ Wk,
                                            float* __restrict__ a,
                                            float* __restrict__ kf) {
    __shared__ float h8[8 * DIM];
    int t0 = blockIdx.x * 8;
    for (int i = threadIdx.x; i < 8 * DIM; i += 128) {
        int t = t0 + (i >> 9);
        h8[i] = (t < N_SEQ) ? h[(size_t)t * DIM + (i & 511)] : 0.f;
    }
    __syncthreads();
    int c = threadIdx.x;
    int r = c & 63;
    const float* W = ((c < 64) ? Wq : Wk) + r;
    float acc[8] = {};
    for (int d = 0; d < DIM; d++) {
        float w = W[(size_t)d * RANK];
        #pragma unroll
        for (int i = 0; i < 8; i++) acc[i] += h8[i * DIM + d] * w;
    }
    float* out = (c < 64) ? a : kf;
    #pragma unroll
    for (int i = 0; i < 8; i++) {
        int t = t0 + i;
        if (t < N_SEQ) out[(size_t)t * RANK + r] = acc[i];
    }
}

// ---------------------------------------------------------------- signed sliding-window attention + LN
__global__ __launch_bounds__(64) void k_attn(const float* __restrict__ hin,
                                             const float* __restrict__ a,
                                             const float* __restrict__ kf,
                                             const float* __restrict__ g,
                                             const float* __restrict__ b,
                                             float* __restrict__ hout) {
    __shared__ float a_s[64];
    __shared__ float w_s[64];
    int t = blockIdx.x;
    int lane = threadIdx.x;
    a_s[lane] = a[(size_t)t * RANK + lane];
    __syncthreads();
    int src  = t - 63 + lane;
    int srcc = src < 0 ? 0 : src;
    const float* kr_ = kf + (size_t)srcc * RANK;
    float sc = 0.f;
    #pragma unroll 8
    for (int r = 0; r < RANK; r++) sc += a_s[r] * kr_[r];
    sc *= SCALE;
    float logit = (src >= 0) ? fabsf(sc) : -1e9f;
    float m = logit;
    #pragma unroll
    for (int off = 32; off >= 1; off >>= 1) m = fmaxf(m, __shfl_xor(m, off, 64));
    float e = expf(logit - m);
    float sum = e;
    #pragma unroll
    for (int off = 32; off >= 1; off >>= 1) sum += __shfl_xor(sum, off, 64);
    float sgn = (sc > 0.f) ? 1.f : ((sc < 0.f) ? -1.f : 0.f);
    float w = (src >= 0) ? (e / sum) * sgn : 0.f;
    w_s[lane] = w;
    __syncthreads();
    float acc[8] = {};
    int basej = t - 63;
    for (int j = 0; j < 64; j++) {
        float wj = w_s[j];
        int sj = basej + j; sj = sj < 0 ? 0 : sj;
        const float* hr = hin + (size_t)sj * DIM + lane;
        #pragma unroll
        for (int u = 0; u < 8; u++) acc[u] += wj * hr[u * 64];
    }
    const float* hrow = hin + (size_t)t * DIM + lane;
    float x[8]; float sum2 = 0.f, sq = 0.f;
    #pragma unroll
    for (int u = 0; u < 8; u++) {
        x[u] = hrow[u * 64] + acc[u];
        sum2 += x[u]; sq += x[u] * x[u];
    }
    #pragma unroll
    for (int off = 32; off >= 1; off >>= 1) {
        sum2 += __shfl_xor(sum2, off, 64);
        sq   += __shfl_xor(sq,   off, 64);
    }
    float mean = sum2 * (1.f / DIM);
    float var  = sq * (1.f / DIM) - mean * mean;
    float inv  = rsqrtf(var + LN_EPS);
    #pragma unroll
    for (int u = 0; u < 8; u++) {
        int d = lane + u * 64;
        hout[(size_t)t * DIM + d] = (x[u] - mean) * inv * g[d] + b[d];
    }
}

// ---------------------------------------------------------------- final LN into padded (2048,512) buffer
__global__ __launch_bounds__(64) void k_ln_out(const float* __restrict__ hin,
                                               const float* __restrict__ g,
                                               const float* __restrict__ b,
                                               float* __restrict__ hP) {
    int t = blockIdx.x;
    int lane = threadIdx.x;
    if (t >= N_SEQ) {
        #pragma unroll
        for (int u = 0; u < 8; u++) hP[(size_t)t * DIM + lane + u * 64] = 0.f;
        return;
    }
    const float* hrow = hin + (size_t)t * DIM + lane;
    float x[8]; float sum = 0.f, sq = 0.f;
    #pragma unroll
    for (int u = 0; u < 8; u++) {
        x[u] = hrow[u * 64];
        sum += x[u]; sq += x[u] * x[u];
    }
    #pragma unroll
    for (int off = 32; off >= 1; off >>= 1) {
        sum += __shfl_xor(sum, off, 64);
        sq  += __shfl_xor(sq,  off, 64);
    }
    float mean = sum * (1.f / DIM);
    float var  = sq * (1.f / DIM) - mean * mean;
    float inv  = rsqrtf(var + LN_EPS);
    #pragma unroll
    for (int u = 0; u < 8; u++) {
        int d = lane + u * 64;
        hP[(size_t)t * DIM + d] = (x[u] - mean) * inv * g[d] + b[d];
    }
}

// ---------------------------------------------------------------- logits = A(2048,512) @ E^T(512,32000), bf16 MFMA
__global__ __launch_bounds__(256) void k_gemm(const float* __restrict__ A,
                                              const float* __restrict__ E,
                                              float* __restrict__ C) {
    __shared__ unsigned short As[128 * 64];
    __shared__ unsigned short Bs[128 * 64];
    int bm = blockIdx.y, bn = blockIdx.x;
    int tid = threadIdx.x;
    int lane = tid & 63, wave = tid >> 6;
    int wm = (wave >> 1) << 6, wn = (wave & 1) << 6;
    floatx4 acc[4][4] = {};
    for (int k0 = 0; k0 < DIM; k0 += 64) {
        #pragma unroll
        for (int ch = 0; ch < 8; ch++) {
            int f4 = ch * 256 + tid;
            int el = f4 * 4;
            int row = el >> 6;
            int kk = el & 63;
            int csw = (kk >> 3) ^ (row & 7);
            int dst = row * 64 + csw * 8 + (kk & 7);
            float4 av = *(const float4*)(A + (size_t)(bm * 128 + row) * DIM + k0 + kk);
            ushortx4 ua = { f2bf(av.x), f2bf(av.y), f2bf(av.z), f2bf(av.w) };
            *(ushortx4*)&As[dst] = ua;
            float4 bv = *(const float4*)(E + (size_t)(bn * 128 + row) * DIM + k0 + kk);
            ushortx4 ub = { f2bf(bv.x), f2bf(bv.y), f2bf(bv.z), f2bf(bv.w) };
            *(ushortx4*)&Bs[dst] = ub;
        }
        __syncthreads();
        int mr = lane & 15, qd = lane >> 4;
        #pragma unroll
        for (int kh = 0; kh < 2; kh++) {
            bf16x8 af[4], bfr[4];
            #pragma unroll
            for (int i = 0; i < 4; i++) {
                int row = wm + i * 16 + mr;
                int c = kh * 4 + qd;
                af[i] = *(const bf16x8*)&As[row * 64 + ((c ^ (row & 7)) << 3)];
            }
            #pragma unroll
            for (int j = 0; j < 4; j++) {
                int row = wn + j * 16 + mr;
                int c = kh * 4 + qd;
                bfr[j] = *(const bf16x8*)&Bs[row * 64 + ((c ^ (row & 7)) << 3)];
            }
            #pragma unroll
            for (int i = 0; i < 4; i++)
                #pragma unroll
                for (int j = 0; j < 4; j++)
                    acc[i][j] = __builtin_amdgcn_mfma_f32_16x16x32_bf16(af[i], bfr[j], acc[i][j], 0, 0, 0);
        }
        __syncthreads();
    }
    int lr = lane >> 4, lc = lane & 15;
    #pragma unroll
    for (int i = 0; i < 4; i++)
        #pragma unroll
        for (int j = 0; j < 4; j++)
            #pragma unroll
            for (int reg = 0; reg < 4; reg++) {
                int gr = bm * 128 + wm + i * 16 + lr * 4 + reg;
                int gc = bn * 128 + wn + j * 16 + lc;
                if (gr < N_SEQ) C[(size_t)gr * VOCAB + gc] = acc[i][j][reg];
            }
}

// ----------------------------------------------------------------
extern "C" void kernel_launch(void* const* d_in, const int* in_sizes, int n_in,
                              void* d_out, int out_size, void* d_ws, size_t ws_size,
                              hipStream_t stream) {
    (void)in_sizes; (void)n_in; (void)out_size; (void)ws_size;
    const int*   ids  = (const int*)d_in[0];
    const float* E    = (const float*)d_in[1];
    const float* Ur   = (const float*)d_in[2];
    const float* Vr   = (const float*)d_in[3];
    const float* m0   = (const float*)d_in[4];
    const float* m1   = (const float*)d_in[5];
    const float* m2   = (const float*)d_in[6];
    const float* Wp   = (const float*)d_in[7];
    const float* Wq   = (const float*)d_in[8];
    const float* Wk   = (const float*)d_in[9];
    const float* lig  = (const float*)d_in[10];
    const float* lib  = (const float*)d_in[11];
    const float* lpg  = (const float*)d_in[12];
    const float* lpb  = (const float*)d_in[13];
    const float* log_ = (const float*)d_in[14];
    const float* lob  = (const float*)d_in[15];
    float* out = (float*)d_out;

    float* ws = (float*)d_ws;
    size_t off = 0;
    auto alloc = [&](size_t n) { float* p = ws + off; off += (n + 255) & ~(size_t)255; return p; };
    float* s   = alloc((size_t)N_SEQ * DIM);
    float* q   = alloc((size_t)N_SEQ * DIM);
    float* qr  = alloc((size_t)3 * N_SEQ * RANK);
    float* xv  = alloc((size_t)3 * N_SEQ * RANK);
    float* kr  = alloc((size_t)336 * RANK);
    float* sel = alloc((size_t)3 * N_SEQ * 16 * 2);
    float* hA  = alloc((size_t)N_SEQ * DIM);
    float* hB  = alloc((size_t)N_SEQ * DIM);
    float* ab  = alloc((size_t)N_SEQ * RANK);
    float* kfb = alloc((size_t)N_SEQ * RANK);
    float* hP  = alloc((size_t)2048 * DIM);

    k_embed     <<<N_SEQ, 128, 0, stream>>>(ids, E, s, q);
    k_proj      <<<256, 384, 0, stream>>>(s, Ur, Vr, qr, xv);
    k_kr0       <<<336, 64, 0, stream>>>(m0, m1, m2, Vr, kr);
    k_select_all<<<3, 64, 0, stream>>>(qr, xv, kr, (float2*)sel);
    k_apply_all <<<24, 64, 0, stream>>>(s, (const float2*)sel, m0, m1, m2, q);
    k_wproj_ln  <<<256, 256, 0, stream>>>(q, Wp, lig, lib, hA);
    k_qk        <<<256, 128, 0, stream>>>(hA, Wq, Wk, ab, kfb);
    k_attn      <<<N_SEQ, 64, 0, stream>>>(hA, ab, kfb, lpg, lpb, hB);
    k_qk        <<<256, 128, 0, stream>>>(hB, Wq + DIM * RANK, Wk + DIM * RANK, ab, kfb);
    k_attn      <<<N_SEQ, 64, 0, stream>>>(hB, ab, kfb, lpg + DIM, lpb + DIM, hA);
    k_ln_out    <<<2048, 64, 0, stream>>>(hA, log_, lob, hP);
    dim3 gg(VOCAB / 128, 2048 / 128);
    k_gemm      <<<gg, 256, 0, stream>>>(hP, E, out);
}

// Round 2
// 9121.663 us; speedup vs baseline: 3.4534x; 1.1717x over previous
//
#include <hip/hip_runtime.h>

#define N_SEQ 2047
#define DIM   512
#define RANK  64
#define VOCAB 32000
#define SCALE 0.125f
#define LN_EPS 1e-5f

typedef __attribute__((ext_vector_type(4))) float  floatx4;
typedef __attribute__((ext_vector_type(8))) __bf16 bf16x8;
typedef __attribute__((ext_vector_type(4))) unsigned short ushortx4;

__device__ __forceinline__ unsigned short f2bf(float x) {
    unsigned int u = __builtin_bit_cast(unsigned int, x);
    return (unsigned short)((u + 0x7fffu + ((u >> 16) & 1u)) >> 16);
}

// DPP-based wave64 sum reduction (identity 0), result broadcast (uniform) to all lanes.
__device__ __forceinline__ float wave_sum64(float x) {
    int xi;
    xi = __builtin_amdgcn_update_dpp(0, __float_as_int(x), 0x111, 0xf, 0xf, false); x += __int_as_float(xi); // row_shr:1
    xi = __builtin_amdgcn_update_dpp(0, __float_as_int(x), 0x112, 0xf, 0xf, false); x += __int_as_float(xi); // row_shr:2
    xi = __builtin_amdgcn_update_dpp(0, __float_as_int(x), 0x114, 0xf, 0xf, false); x += __int_as_float(xi); // row_shr:4
    xi = __builtin_amdgcn_update_dpp(0, __float_as_int(x), 0x118, 0xf, 0xf, false); x += __int_as_float(xi); // row_shr:8
    xi = __builtin_amdgcn_update_dpp(0, __float_as_int(x), 0x142, 0xa, 0xf, false); x += __int_as_float(xi); // row_bcast15
    xi = __builtin_amdgcn_update_dpp(0, __float_as_int(x), 0x143, 0x8, 0xf, false); x += __int_as_float(xi); // row_bcast31
    return __int_as_float(__builtin_amdgcn_readlane(__float_as_int(x), 63));
}

// ---------------------------------------------------------------- embedding
__global__ __launch_bounds__(128) void k_embed(const int* __restrict__ ids,
                                               const float* __restrict__ E,
                                               float* __restrict__ s,
                                               float* __restrict__ q) {
    int n = blockIdx.x;
    int id = ids[n + 1];
    float4 v = ((const float4*)(E + (size_t)id * DIM))[threadIdx.x];
    ((float4*)(s + (size_t)n * DIM))[threadIdx.x] = v;
    ((float4*)(q + (size_t)n * DIM))[threadIdx.x] = v;
}

// ---------------------------------------------------------------- qr/xv projections
__global__ __launch_bounds__(384) void k_proj(const float* __restrict__ s,
                                              const float* __restrict__ Ur,
                                              const float* __restrict__ Vr,
                                              float* __restrict__ qr,
                                              float* __restrict__ xv) {
    __shared__ float s8[8 * DIM];
    int t0 = blockIdx.x * 8;
    for (int i = threadIdx.x; i < 8 * DIM; i += 384) {
        int t = t0 + (i >> 9);
        s8[i] = (t < N_SEQ) ? s[(size_t)t * DIM + (i & 511)] : 0.f;
    }
    __syncthreads();
    int c = threadIdx.x;
    int l = (c % 192) / 64;
    int r = c & 63;
    const float* W = ((c < 192) ? Ur : Vr) + (size_t)l * DIM * RANK + r;
    float acc[8] = {};
    for (int d = 0; d < DIM; d++) {
        float w = W[(size_t)d * RANK];
        #pragma unroll
        for (int i = 0; i < 8; i++) acc[i] += s8[i * DIM + d] * w;
    }
    float* out = ((c < 192) ? qr : xv) + (size_t)l * N_SEQ * RANK;
    #pragma unroll
    for (int i = 0; i < 8; i++) {
        int t = t0 + i;
        if (t < N_SEQ) out[(size_t)t * RANK + r] = acc[i];
    }
}

// ---------------------------------------------------------------- kr0 = M0 @ Vr[l]
__global__ __launch_bounds__(64) void k_kr0(const float* __restrict__ m0,
                                            const float* __restrict__ m1,
                                            const float* __restrict__ m2,
                                            const float* __restrict__ Vr,
                                            float* __restrict__ kr) {
    __shared__ float mrow[DIM];
    int sl = blockIdx.x;
    int lvl = (sl < 256) ? 0 : (sl < 320 ? 1 : 2);
    const float* src = (lvl == 0) ? m0 + (size_t)sl * DIM
                     : (lvl == 1) ? m1 + (size_t)(sl - 256) * DIM
                                  : m2 + (size_t)(sl - 320) * DIM;
    for (int i = threadIdx.x; i < DIM / 4; i += 64)
        ((float4*)mrow)[i] = ((const float4*)src)[i];
    __syncthreads();
    const float* W = Vr + (size_t)lvl * DIM * RANK + threadIdx.x;
    float acc = 0.f;
    for (int d = 0; d < DIM; d++) acc += mrow[d] * W[(size_t)d * RANK];
    kr[(size_t)sl * RANK + threadIdx.x] = acc;
}

// ---------------------------------------------------------------- Phase A: pipelined selection scan
// 5 waves/block, 1 block/level. Wave 0 = searcher; waves 1..4 own 64 slots each
// (krr[64] regs/lane, no spills). While wave 0 searches step t's scores, workers
// pre-compute raw scores for t+1 (qr_{t+1}.kr_t) and the rank-1 correction dot
// d = qr_{t+1}.xv_t. After weights publish: scs_{t+1} = SCALE*(raw + gate*w*d),
// and kr update is deferred into the next search window.
template<int S, int IMASK>
__device__ __forceinline__ void select_impl(float (*qs)[32][64], float (*xs)[32][64],
                                            float* scs, float* wsel_s, int* isel_s,
                                            const float* __restrict__ qrl,
                                            const float* __restrict__ xvl,
                                            const float* __restrict__ krl,
                                            float2* __restrict__ selo) {
    constexpr int G = (S + 63) / 64;
    const int tid  = threadIdx.x;
    const int wave = tid >> 6;
    const int lane = tid & 63;
    const unsigned long long ltmask = (1ULL << lane) - 1ULL;

    // prologue: stage rows 0..31, pad scs
    for (int row = wave; row < 32; row += 5) {
        qs[0][row][lane] = qrl[(size_t)row * RANK + lane];
        xs[0][row][lane] = xvl[(size_t)row * RANK + lane];
    }
    if (tid < 256) scs[tid] = -3.0e38f;

    const int  slot     = (wave >= 1) ? (((wave - 1) << 6) + lane) : -1;
    const bool isWorker = (wave >= 1) && (slot < S);

    float krr[RANK];
    if (isWorker) {
        #pragma unroll
        for (int i = 0; i < 16; ++i)
            ((floatx4*)krr)[i] = ((const floatx4*)(krl + (size_t)slot * RANK))[i];
    } else {
        #pragma unroll
        for (int r = 0; r < RANK; ++r) krr[r] = 0.f;
    }

    float qstage = 0.f, xstage = 0.f;
    if (wave == 1) qstage = qrl[(size_t)32 * RANK + lane];
    if (wave == 2) xstage = xvl[(size_t)32 * RANK + lane];

    __syncthreads();

    // initial scores (t = 0)
    if (isWorker) {
        float acc = 0.f;
        #pragma unroll
        for (int i = 0; i < 16; ++i) {
            float4 qf = ((const float4*)qs[0][0])[i];
            acc += qf.x * krr[i*4+0] + qf.y * krr[i*4+1] + qf.z * krr[i*4+2] + qf.w * krr[i*4+3];
        }
        scs[slot] = acc * SCALE;
    }
    float wprev = 0.f;
    __syncthreads();

    for (int t = 0; t < N_SEQ; ++t) {
        const int gate = ((t & IMASK) == 0);
        float sc_raw = 0.f, dgl = 0.f;

        if (wave == 0) {
            // -------- top-16 over scs via 2-bit ballot binary search --------
            float scf[G]; unsigned key[G];
            #pragma unroll
            for (int g = 0; g < G; ++g) {
                float v = scs[(g << 6) + lane];
                scf[g] = v;
                unsigned bb = __float_as_uint(v);
                key[g] = (bb & 0x80000000u) ? ~bb : (bb | 0x80000000u);
            }
            unsigned thr = 0u;
            #pragma unroll
            for (int bit = 30; bit >= 0; bit -= 2) {
                const unsigned cLo = thr | (1u << bit);
                const unsigned cHi = thr | (2u << bit);
                const unsigned cBo = thr | (3u << bit);
                int nLo = 0, nHi = 0, nBo = 0;
                #pragma unroll
                for (int g = 0; g < G; ++g) {
                    nLo += (int)__popcll(__ballot(key[g] >= cLo));
                    nHi += (int)__popcll(__ballot(key[g] >= cHi));
                    nBo += (int)__popcll(__ballot(key[g] >= cBo));
                }
                if (nHi >= 16)      thr = (nBo >= 16) ? cBo : cHi;
                else if (nLo >= 16) thr = cLo;
            }
            unsigned long long beq[G], bsel[G]; bool selq[G];
            int cntgt = 0;
            #pragma unroll
            for (int g = 0; g < G; ++g) {
                cntgt += (int)__popcll(__ballot(key[g] > thr));
                beq[g] = __ballot(key[g] == thr);
            }
            const int needeq = 16 - cntgt;
            int eqpre = 0;
            #pragma unroll
            for (int g = 0; g < G; ++g) {
                const bool isgt = key[g] > thr;
                const bool iseq = key[g] == thr;
                const int eqrank = eqpre + (int)__popcll(beq[g] & ltmask);
                selq[g] = isgt || (iseq && (eqrank < needeq));
                bsel[g] = __ballot(selq[g]);
                eqpre += (int)__popcll(beq[g]);
            }
            const unsigned tb = (thr & 0x80000000u) ? (thr & 0x7fffffffu) : ~thr;
            const float Tf = __uint_as_float(tb);
            float e[G]; float es = 0.f;
            #pragma unroll
            for (int g = 0; g < G; ++g) {
                e[g] = selq[g] ? expf(scf[g] - Tf) : 0.f;
                es += e[g];
            }
            const float inv = 1.f / wave_sum64(es);
            int pb = 0;
            #pragma unroll
            for (int g = 0; g < G; ++g) {
                if (selq[g]) {
                    const int pos = pb + (int)__popcll(bsel[g] & ltmask);
                    const float w = e[g] * inv;
                    const int sl = (g << 6) + lane;
                    float2 o; o.x = w; o.y = __int_as_float(sl);
                    selo[(size_t)t * 16 + pos] = o;
                    wsel_s[pos] = w;
                    isel_s[pos] = sl;
                }
                pb += (int)__popcll(bsel[g]);
            }
        } else {
            // -------- worker window (overlaps the search) --------
            const int tp = (t > 0) ? t - 1 : 0;              // deferred kr update source
            const int tn = t + 1;
            const int tq = (tn < N_SEQ) ? tn : t;            // clamped next row
            const float* xrow_p = xs[(tp >> 5) & 1][tp & 31];
            const float* qrow_n = qs[(tq >> 5) & 1][tq & 31];
            const float* xrow_t = xs[(t  >> 5) & 1][t  & 31];
            if (isWorker) {
                #pragma unroll
                for (int i = 0; i < 16; ++i) {
                    float4 xf = ((const float4*)xrow_p)[i];
                    krr[i*4+0] += wprev * xf.x; krr[i*4+1] += wprev * xf.y;
                    krr[i*4+2] += wprev * xf.z; krr[i*4+3] += wprev * xf.w;
                }
                float acc = 0.f;
                #pragma unroll
                for (int i = 0; i < 16; ++i) {
                    float4 qf = ((const float4*)qrow_n)[i];
                    acc += qf.x * krr[i*4+0] + qf.y * krr[i*4+1]
                         + qf.z * krr[i*4+2] + qf.w * krr[i*4+3];
                }
                sc_raw = acc;
            }
            // rank-1 correction dot (needs all 64 lanes of the wave)
            dgl = wave_sum64(qrow_n[lane] * xrow_t[lane]);
            // async staging: write last iter's load, issue next
            if (wave == 1) {
                const int uw = t + 32;
                if (uw < N_SEQ) qs[(uw >> 5) & 1][uw & 31][lane] = qstage;
                const int ul = t + 33;
                if (ul < N_SEQ) qstage = qrl[(size_t)ul * RANK + lane];
            }
            if (wave == 2) {
                const int uw = t + 32;
                if (uw < N_SEQ) xs[(uw >> 5) & 1][uw & 31][lane] = xstage;
                const int ul = t + 33;
                if (ul < N_SEQ) xstage = xvl[(size_t)ul * RANK + lane];
            }
        }
        __syncthreads();   // B1: weights published
        if (wave != 0) {
            float wloc = 0.f;
            if (isWorker) {
                #pragma unroll
                for (int j = 0; j < 4; ++j) {
                    int4   ii = ((const int4*)isel_s)[j];
                    float4 ww = ((const float4*)wsel_s)[j];
                    wloc = (ii.x == slot) ? ww.x : wloc;
                    wloc = (ii.y == slot) ? ww.y : wloc;
                    wloc = (ii.z == slot) ? ww.z : wloc;
                    wloc = (ii.w == slot) ? ww.w : wloc;
                }
                const float corr = gate ? wloc * dgl : 0.f;
                scs[slot] = (sc_raw + corr) * SCALE;
            }
            wprev = gate ? wloc : 0.f;
        }
        __syncthreads();   // B2: next-step scores ready
    }
}

__global__ __launch_bounds__(320, 1) void k_select_all(const float* __restrict__ qr,
                                                       const float* __restrict__ xv,
                                                       const float* __restrict__ kr0,
                                                       float2* __restrict__ sel) {
    __shared__ float qs[2][32][64];
    __shared__ float xs[2][32][64];
    __shared__ float scs[256];
    __shared__ float wsel_s[16];
    __shared__ int   isel_s[16];
    const int l = blockIdx.x;
    if (l == 0)
        select_impl<256, 0>(qs, xs, scs, wsel_s, isel_s, qr, xv, kr0, sel);
    else if (l == 1)
        select_impl<64, 3>(qs, xs, scs, wsel_s, isel_s,
                           qr + (size_t)N_SEQ * RANK, xv + (size_t)N_SEQ * RANK,
                           kr0 + 256 * RANK, sel + (size_t)N_SEQ * 16);
    else
        select_impl<16, 15>(qs, xs, scs, wsel_s, isel_s,
                            qr + (size_t)2 * N_SEQ * RANK, xv + (size_t)2 * N_SEQ * RANK,
                            kr0 + 320 * RANK, sel + (size_t)2 * N_SEQ * 16);
}

// ---------------------------------------------------------------- Phase B: apply scan
template<int S, int IMASK>
__device__ __forceinline__ void apply_impl(float* Ml,
                                           const float* __restrict__ sA,
                                           const float2* __restrict__ selo,
                                           const float* __restrict__ Msrc,
                                           float* __restrict__ q, int chunk) {
    const int lane = threadIdx.x;
    const int c0 = chunk * 64;
    for (int sl = 0; sl < S; ++sl)
        Ml[sl * 64 + lane] = Msrc[(size_t)sl * DIM + c0 + lane];
    __syncthreads();

    float4 svc[8];
    #pragma unroll
    for (int k = 0; k < 8; ++k) svc[k] = ((const float4*)selo)[k];
    float scc = sA[c0 + lane];

    for (int t = 0; t < N_SEQ; ++t) {
        float4 svn[8]; float scn;
        const int tn = (t + 1 < N_SEQ) ? t + 1 : t;
        #pragma unroll
        for (int k = 0; k < 8; ++k) svn[k] = ((const float4*)(selo + (size_t)tn * 16))[k];
        scn = sA[(size_t)tn * DIM + c0 + lane];

        const bool gate = (t & IMASK) == 0;
        float acc = 0.f;
        #pragma unroll
        for (int k = 0; k < 8; ++k) {
            const float w0 = svc[k].x; const int i0 = __float_as_int(svc[k].y);
            const float w1 = svc[k].z; const int i1 = __float_as_int(svc[k].w);
            const float m0v = Ml[i0 * 64 + lane];
            const float m1v = Ml[i1 * 64 + lane];
            acc += w0 * m0v;
            acc += w1 * m1v;
            if (gate) {
                Ml[i0 * 64 + lane] = m0v + w0 * scc;
                Ml[i1 * 64 + lane] = m1v + w1 * scc;
            }
        }
        atomicAdd(&q[(size_t)t * DIM + c0 + lane], acc);
        #pragma unroll
        for (int k = 0; k < 8; ++k) svc[k] = svn[k];
        scc = scn;
    }
}

__global__ __launch_bounds__(64) void k_apply_all(const float* __restrict__ s,
                                                  const float2* __restrict__ sel,
                                                  const float* __restrict__ m0,
                                                  const float* __restrict__ m1,
                                                  const float* __restrict__ m2,
                                                  float* __restrict__ q) {
    __shared__ float Ml[256 * 64];
    const int b = blockIdx.x;
    if (b < 8)
        apply_impl<256, 0>(Ml, s, sel, m0, q, b);
    else if (b < 16)
        apply_impl<64, 3>(Ml, s, sel + (size_t)N_SEQ * 16, m1, q, b - 8);
    else
        apply_impl<16, 15>(Ml, s, sel + (size_t)2 * N_SEQ * 16, m2, q, b - 16);
}

// ---------------------------------------------------------------- h = LN(q @ Wproj^T)
__global__ __launch_bounds__(256) void k_wproj_ln(const float* __restrict__ q,
                                                  const float* __restrict__ Wp,
                                                  const float* __restrict__ g,
                                                  const float* __restrict__ b,
                                                  float* __restrict__ h) {
    __shared__ float q8[8 * DIM];
    __shared__ float hp[8 * DIM];
    int t0 = blockIdx.x * 8;
    for (int i = threadIdx.x; i < 8 * DIM; i += 256) {
        int t = t0 + (i >> 9);
        q8[i] = (t < N_SEQ) ? q[(size_t)t * DIM + (i & 511)] : 0.f;
    }
    __syncthreads();
    int c0 = threadIdx.x * 2;
    float acc0[8] = {}, acc1[8] = {};
    const float* w0 = Wp + (size_t)c0 * DIM;
    const float* w1 = w0 + DIM;
    for (int d = 0; d < DIM; d++) {
        float a0 = w0[d], a1 = w1[d];
        #pragma unroll
        for (int i = 0; i < 8; i++) {
            float qv = q8[i * DIM + d];
            acc0[i] += qv * a0;
            acc1[i] += qv * a1;
        }
    }
    #pragma unroll
    for (int i = 0; i < 8; i++) {
        hp[i * DIM + c0]     = acc0[i];
        hp[i * DIM + c0 + 1] = acc1[i];
    }
    __syncthreads();
    int rowi = threadIdx.x >> 5;
    int l32  = threadIdx.x & 31;
    int t = t0 + rowi;
    if (t < N_SEQ) {
        float sum = 0.f, sq = 0.f;
        #pragma unroll
        for (int u = 0; u < 16; u++) {
            float x = hp[rowi * DIM + l32 + u * 32];
            sum += x; sq += x * x;
        }
        #pragma unroll
        for (int off = 16; off >= 1; off >>= 1) {
            sum += __shfl_xor(sum, off, 32);
            sq  += __shfl_xor(sq,  off, 32);
        }
        float mean = sum * (1.f / DIM);
        float var  = sq * (1.f / DIM) - mean * mean;
        float inv  = rsqrtf(var + LN_EPS);
        #pragma unroll
        for (int u = 0; u < 16; u++) {
            int d = l32 + u * 32;
            float x = hp[rowi * DIM + d];
            h[(size_t)t * DIM + d] = (x - mean) * inv * g[d] + b[d];
        }
    }
}

// ---------------------------------------------------------------- a = h@Wq, kf = h@Wk
__global__ __launch_bounds__(128) void k_qk(const float* __restrict__ h,
                                            const float* __restrict__ Wq,
                                            const float* __restrict__ Wk,
                                            float* __restrict__ a,
                                            float* __restrict__ kf) {
    __shared__ float h8[8 * DIM];
    int t0 = blockIdx.x * 8;
    for (int i = threadIdx.x; i < 8 * DIM; i += 128) {
        int t = t0 + (i >> 9);
        h8[i] = (t < N_SEQ) ? h[(size_t)t * DIM + (i & 511)] : 0.f;
    }
    __syncthreads();
    int c = threadIdx.x;
    int r = c & 63;
    const float* W = ((c < 64) ? Wq : Wk) + r;
    float acc[8] = {};
    for (int d = 0; d < DIM; d++) {
        float w = W[(size_t)d * RANK];
        #pragma unroll
        for (int i = 0; i < 8; i++) acc[i] += h8[i * DIM + d] * w;
    }
    float* out = (c < 64) ? a : kf;
    #pragma unroll
    for (int i = 0; i < 8; i++) {
        int t = t0 + i;
        if (t < N_SEQ) out[(size_t)t * RANK + r] = acc[i];
    }
}

// ---------------------------------------------------------------- signed sliding-window attention + LN
__global__ __launch_bounds__(64) void k_attn(const float* __restrict__ hin,
                                             const float* __restrict__ a,
                                             const float* __restrict__ kf,
                                             const float* __restrict__ g,
                                             const float* __restrict__ b,
                                             float* __restrict__ hout) {
    __shared__ float a_s[64];
    __shared__ float w_s[64];
    int t = blockIdx.x;
    int lane = threadIdx.x;
    a_s[lane] = a[(size_t)t * RANK + lane];
    __syncthreads();
    int src  = t - 63 + lane;
    int srcc = src < 0 ? 0 : src;
    const float* kr_ = kf + (size_t)srcc * RANK;
    float sc = 0.f;
    #pragma unroll 8
    for (int r = 0; r < RANK; r++) sc += a_s[r] * kr_[r];
    sc *= SCALE;
    float logit = (src >= 0) ? fabsf(sc) : -1e9f;
    float m = logit;
    #pragma unroll
    for (int off = 32; off >= 1; off >>= 1) m = fmaxf(m, __shfl_xor(m, off, 64));
    float e = expf(logit - m);
    float sum = e;
    #pragma unroll
    for (int off = 32; off >= 1; off >>= 1) sum += __shfl_xor(sum, off, 64);
    float sgn = (sc > 0.f) ? 1.f : ((sc < 0.f) ? -1.f : 0.f);
    float w = (src >= 0) ? (e / sum) * sgn : 0.f;
    w_s[lane] = w;
    __syncthreads();
    float acc[8] = {};
    int basej = t - 63;
    for (int j = 0; j < 64; j++) {
        float wj = w_s[j];
        int sj = basej + j; sj = sj < 0 ? 0 : sj;
        const float* hr = hin + (size_t)sj * DIM + lane;
        #pragma unroll
        for (int u = 0; u < 8; u++) acc[u] += wj * hr[u * 64];
    }
    const float* hrow = hin + (size_t)t * DIM + lane;
    float x[8]; float sum2 = 0.f, sq = 0.f;
    #pragma unroll
    for (int u = 0; u < 8; u++) {
        x[u] = hrow[u * 64] + acc[u];
        sum2 += x[u]; sq += x[u] * x[u];
    }
    #pragma unroll
    for (int off = 32; off >= 1; off >>= 1) {
        sum2 += __shfl_xor(sum2, off, 64);
        sq   += __shfl_xor(sq,   off, 64);
    }
    float mean = sum2 * (1.f / DIM);
    float var  = sq * (1.f / DIM) - mean * mean;
    float inv  = rsqrtf(var + LN_EPS);
    #pragma unroll
    for (int u = 0; u < 8; u++) {
        int d = lane + u * 64;
        hout[(size_t)t * DIM + d] = (x[u] - mean) * inv * g[d] + b[d];
    }
}

// ---------------------------------------------------------------- final LN into padded (2048,512) buffer
__global__ __launch_bounds__(64) void k_ln_out(const float* __restrict__ hin,
                                               const float* __restrict__ g,
                                               const float* __restrict__ b,
                                               float* __restrict__ hP) {
    int t = blockIdx.x;
    int lane = threadIdx.x;
    if (t >= N_SEQ) {
        #pragma unroll
        for (int u = 0; u < 8; u++) hP[(size_t)t * DIM + lane + u * 64] = 0.f;
        return;
    }
    const float* hrow = hin + (size_t)t * DIM + lane;
    float x[8]; float sum = 0.f, sq = 0.f;
    #pragma unroll
    for (int u = 0; u < 8; u++) {
        x[u] = hrow[u * 64];
        sum += x[u]; sq += x[u] * x[u];
    }
    #pragma unroll
    for (int off = 32; off >= 1; off >>= 1) {
        sum += __shfl_xor(sum, off, 64);
        sq  += __shfl_xor(sq,  off, 64);
    }
    float mean = sum * (1.f / DIM);
    float var  = sq * (1.f / DIM) - mean * mean;
    float inv  = rsqrtf(var + LN_EPS);
    #pragma unroll
    for (int u = 0; u < 8; u++) {
        int d = lane + u * 64;
        hP[(size_t)t * DIM + d] = (x[u] - mean) * inv * g[d] + b[d];
    }
}

// ---------------------------------------------------------------- logits = A(2048,512) @ E^T(512,32000), bf16 MFMA
__global__ __launch_bounds__(256) void k_gemm(const float* __restrict__ A,
                                              const float* __restrict__ E,
                                              float* __restrict__ C) {
    __shared__ unsigned short As[128 * 64];
    __shared__ unsigned short Bs[128 * 64];
    int bm = blockIdx.y, bn = blockIdx.x;
    int tid = threadIdx.x;
    int lane = tid & 63, wave = tid >> 6;
    int wm = (wave >> 1) << 6, wn = (wave & 1) << 6;
    floatx4 acc[4][4] = {};
    for (int k0 = 0; k0 < DIM; k0 += 64) {
        #pragma unroll
        for (int ch = 0; ch < 8; ch++) {
            int f4 = ch * 256 + tid;
            int el = f4 * 4;
            int row = el >> 6;
            int kk = el & 63;
            int csw = (kk >> 3) ^ (row & 7);
            int dst = row * 64 + csw * 8 + (kk & 7);
            float4 av = *(const float4*)(A + (size_t)(bm * 128 + row) * DIM + k0 + kk);
            ushortx4 ua = { f2bf(av.x), f2bf(av.y), f2bf(av.z), f2bf(av.w) };
            *(ushortx4*)&As[dst] = ua;
            float4 bv = *(const float4*)(E + (size_t)(bn * 128 + row) * DIM + k0 + kk);
            ushortx4 ub = { f2bf(bv.x), f2bf(bv.y), f2bf(bv.z), f2bf(bv.w) };
            *(ushortx4*)&Bs[dst] = ub;
        }
        __syncthreads();
        int mr = lane & 15, qd = lane >> 4;
        #pragma unroll
        for (int kh = 0; kh < 2; kh++) {
            bf16x8 af[4], bfr[4];
            #pragma unroll
            for (int i = 0; i < 4; i++) {
                int row = wm + i * 16 + mr;
                int c = kh * 4 + qd;
                af[i] = *(const bf16x8*)&As[row * 64 + ((c ^ (row & 7)) << 3)];
            }
            #pragma unroll
            for (int j = 0; j < 4; j++) {
                int row = wn + j * 16 + mr;
                int c = kh * 4 + qd;
                bfr[j] = *(const bf16x8*)&Bs[row * 64 + ((c ^ (row & 7)) << 3)];
            }
            #pragma unroll
            for (int i = 0; i < 4; i++)
                #pragma unroll
                for (int j = 0; j < 4; j++)
                    acc[i][j] = __builtin_amdgcn_mfma_f32_16x16x32_bf16(af[i], bfr[j], acc[i][j], 0, 0, 0);
        }
        __syncthreads();
    }
    int lr = lane >> 4, lc = lane & 15;
    #pragma unroll
    for (int i = 0; i < 4; i++)
        #pragma unroll
        for (int j = 0; j < 4; j++)
            #pragma unroll
            for (int reg = 0; reg < 4; reg++) {
                int gr = bm * 128 + wm + i * 16 + lr * 4 + reg;
                int gc = bn * 128 + wn + j * 16 + lc;
                if (gr < N_SEQ) C[(size_t)gr * VOCAB + gc] = acc[i][j][reg];
            }
}

// ----------------------------------------------------------------
extern "C" void kernel_launch(void* const* d_in, const int* in_sizes, int n_in,
                              void* d_out, int out_size, void* d_ws, size_t ws_size,
                              hipStream_t stream) {
    (void)in_sizes; (void)n_in; (void)out_size; (void)ws_size;
    const int*   ids  = (const int*)d_in[0];
    const float* E    = (const float*)d_in[1];
    const float* Ur   = (const float*)d_in[2];
    const float* Vr   = (const float*)d_in[3];
    const float* m0   = (const float*)d_in[4];
    const float* m1   = (const float*)d_in[5];
    const float* m2   = (const float*)d_in[6];
    const float* Wp   = (const float*)d_in[7];
    const float* Wq   = (const float*)d_in[8];
    const float* Wk   = (const float*)d_in[9];
    const float* lig  = (const float*)d_in[10];
    const float* lib  = (const float*)d_in[11];
    const float* lpg  = (const float*)d_in[12];
    const float* lpb  = (const float*)d_in[13];
    const float* log_ = (const float*)d_in[14];
    const float* lob  = (const float*)d_in[15];
    float* out = (float*)d_out;

    float* ws = (float*)d_ws;
    size_t off = 0;
    auto alloc = [&](size_t n) { float* p = ws + off; off += (n + 255) & ~(size_t)255; return p; };
    float* s   = alloc((size_t)N_SEQ * DIM);
    float* q   = alloc((size_t)N_SEQ * DIM);
    float* qr  = alloc((size_t)3 * N_SEQ * RANK);
    float* xv  = alloc((size_t)3 * N_SEQ * RANK);
    float* kr  = alloc((size_t)336 * RANK);
    float* sel = alloc((size_t)3 * N_SEQ * 16 * 2);
    float* hA  = alloc((size_t)N_SEQ * DIM);
    float* hB  = alloc((size_t)N_SEQ * DIM);
    float* ab  = alloc((size_t)N_SEQ * RANK);
    float* kfb = alloc((size_t)N_SEQ * RANK);
    float* hP  = alloc((size_t)2048 * DIM);

    k_embed     <<<N_SEQ, 128, 0, stream>>>(ids, E, s, q);
    k_proj      <<<256, 384, 0, stream>>>(s, Ur, Vr, qr, xv);
    k_kr0       <<<336, 64, 0, stream>>>(m0, m1, m2, Vr, kr);
    k_select_all<<<3, 320, 0, stream>>>(qr, xv, kr, (float2*)sel);
    k_apply_all <<<24, 64, 0, stream>>>(s, (const float2*)sel, m0, m1, m2, q);
    k_wproj_ln  <<<256, 256, 0, stream>>>(q, Wp, lig, lib, hA);
    k_qk        <<<256, 128, 0, stream>>>(hA, Wq, Wk, ab, kfb);
    k_attn      <<<N_SEQ, 64, 0, stream>>>(hA, ab, kfb, lpg, lpb, hB);
    k_qk        <<<256, 128, 0, stream>>>(hB, Wq + DIM * RANK, Wk + DIM * RANK, ab, kfb);
    k_attn      <<<N_SEQ, 64, 0, stream>>>(hB, ab, kfb, lpg + DIM, lpb + DIM, hA);
    k_ln_out    <<<2048, 64, 0, stream>>>(hA, log_, lob, hP);
    dim3 gg(VOCAB / 128, 2048 / 128);
    k_gemm      <<<gg, 256, 0, stream>>>(hP, E, out);
}